// Round 2
// baseline (532.805 us; speedup 1.0000x reference)
//
#include <hip/hip_runtime.h>
#include <stdint.h>

typedef unsigned short u16;
typedef __attribute__((ext_vector_type(8))) short short8;   // 8 bf16 in 4 VGPRs (MFMA A/B frag)
typedef __attribute__((ext_vector_type(4))) float floatx4;  // MFMA C/D frag

__device__ inline float b2f(u16 u) {
  union { uint32_t i; float f; } x; x.i = ((uint32_t)u) << 16; return x.f;
}
__device__ inline u16 f2b(float f) {
  union { float f; uint32_t i; } x; x.f = f;
  uint32_t r = (x.i + 0x7FFFu + ((x.i >> 16) & 1u)) >> 16;
  return (u16)r;
}
__device__ inline float gelu_f(float v) {
  return 0.5f * v * (1.0f + erff(v * 0.70710678118654752440f));
}

#define MFMA16(a, b, c) __builtin_amdgcn_mfma_f32_16x16x32_bf16((a), (b), (c), 0, 0, 0)

// ------------- transpose+convert: dst[C][R] = bf16(src[R][C]) (src fp32) ----------
__global__ __launch_bounds__(256)
void tpose_kernel(const float* __restrict__ src, u16* __restrict__ dst, int R, int C) {
  __shared__ u16 t[32][33];
  int bx = blockIdx.x * 32;  // col tile of src
  int by = blockIdx.y * 32;  // row tile of src
  int tx = threadIdx.x & 31, ty = threadIdx.x >> 5;  // 32 x 8
  for (int i = 0; i < 32; i += 8)
    t[ty + i][tx] = f2b(src[(size_t)(by + ty + i) * C + bx + tx]);
  __syncthreads();
  for (int i = 0; i < 32; i += 8)
    dst[(size_t)(bx + ty + i) * R + by + tx] = t[tx][ty + i];
}

// ------------- LayerNorm D=128, fp32 source -> bf16 out; one wave per row ---------
__global__ __launch_bounds__(256)
void ln128_f32_kernel(const float* __restrict__ X, const float* __restrict__ g,
                      const float* __restrict__ bb, u16* __restrict__ Y) {
  int tid = threadIdx.x, w = tid >> 6, lane = tid & 63;
  int row = blockIdx.x * 4 + w;
  const float* xr = X + (size_t)row * 128;
  float2 xv = *(const float2*)(xr + lane * 2);
  float x0 = xv.x, x1 = xv.y;
  float s = x0 + x1, s2 = x0 * x0 + x1 * x1;
  for (int m = 1; m < 64; m <<= 1) { s += __shfl_xor(s, m, 64); s2 += __shfl_xor(s2, m, 64); }
  float mean = s * (1.0f / 128.0f);
  float var = s2 * (1.0f / 128.0f) - mean * mean;
  float rstd = 1.0f / sqrtf(var + 1e-5f);
  float2 gv = *(const float2*)(g + lane * 2);
  float2 bv = *(const float2*)(bb + lane * 2);
  float y0 = (x0 - mean) * rstd * gv.x + bv.x;
  float y1 = (x1 - mean) * rstd * gv.y + bv.y;
  *(uint32_t*)(Y + (size_t)row * 128 + lane * 2) =
      (uint32_t)f2b(y0) | ((uint32_t)f2b(y1) << 16);
}

// ------------- LayerNorm D=128, bf16 source -> bf16 out; one wave per row ---------
__global__ __launch_bounds__(256)
void ln128_bf16_kernel(const u16* __restrict__ X, const float* __restrict__ g,
                       const float* __restrict__ bb, u16* __restrict__ Y) {
  int tid = threadIdx.x, w = tid >> 6, lane = tid & 63;
  int row = blockIdx.x * 4 + w;
  const u16* xr = X + (size_t)row * 128;
  uint32_t u = *(const uint32_t*)(xr + lane * 2);
  float x0 = b2f(u & 0xffff), x1 = b2f(u >> 16);
  float s = x0 + x1, s2 = x0 * x0 + x1 * x1;
  for (int m = 1; m < 64; m <<= 1) { s += __shfl_xor(s, m, 64); s2 += __shfl_xor(s2, m, 64); }
  float mean = s * (1.0f / 128.0f);
  float var = s2 * (1.0f / 128.0f) - mean * mean;
  float rstd = 1.0f / sqrtf(var + 1e-5f);
  float2 gv = *(const float2*)(g + lane * 2);
  float2 bv = *(const float2*)(bb + lane * 2);
  float y0 = (x0 - mean) * rstd * gv.x + bv.x;
  float y1 = (x1 - mean) * rstd * gv.y + bv.y;
  *(uint32_t*)(Y + (size_t)row * 128 + lane * 2) =
      (uint32_t)f2b(y0) | ((uint32_t)f2b(y1) << 16);
}

// ------------- LayerNorm D=1536, bf16 source -> bf16 out; one block per row -------
__global__ __launch_bounds__(256)
void ln1536_kernel(const u16* __restrict__ X, const float* __restrict__ g,
                   const float* __restrict__ bb, u16* __restrict__ Y) {
  int row = blockIdx.x, tid = threadIdx.x;
  const u16* xr = X + (size_t)row * 1536;
  uint32_t u0 = *(const uint32_t*)(xr + tid * 6);
  uint32_t u1 = *(const uint32_t*)(xr + tid * 6 + 2);
  uint32_t u2 = *(const uint32_t*)(xr + tid * 6 + 4);
  float v[6] = { b2f(u0 & 0xffff), b2f(u0 >> 16), b2f(u1 & 0xffff),
                 b2f(u1 >> 16),    b2f(u2 & 0xffff), b2f(u2 >> 16) };
  float s = 0.f, s2 = 0.f;
  for (int j = 0; j < 6; j++) { s += v[j]; s2 += v[j] * v[j]; }
  for (int m = 1; m < 64; m <<= 1) { s += __shfl_xor(s, m, 64); s2 += __shfl_xor(s2, m, 64); }
  __shared__ float red[8];
  int w = tid >> 6, lane = tid & 63;
  if (lane == 0) { red[w] = s; red[4 + w] = s2; }
  __syncthreads();
  s = red[0] + red[1] + red[2] + red[3];
  s2 = red[4] + red[5] + red[6] + red[7];
  float mean = s * (1.0f / 1536.0f);
  float var = s2 * (1.0f / 1536.0f) - mean * mean;
  float rstd = 1.0f / sqrtf(var + 1e-5f);
  uint32_t o[3];
  for (int p = 0; p < 3; p++) {
    int c = tid * 6 + p * 2;
    float y0 = (v[p * 2] - mean) * rstd * g[c] + bb[c];
    float y1 = (v[p * 2 + 1] - mean) * rstd * g[c + 1] + bb[c + 1];
    o[p] = (uint32_t)f2b(y0) | ((uint32_t)f2b(y1) << 16);
  }
  u16* yr = Y + (size_t)row * 1536 + tid * 6;
  *(uint32_t*)(yr) = o[0];
  *(uint32_t*)(yr + 2) = o[1];
  *(uint32_t*)(yr + 4) = o[2];
}

// ------------- GEMM: C[M,N] = act(A[M,K] @ BT[N,K]^T + bias (+res)) ---------------
// A,BT bf16; bias fp32; res bf16; OUTT = u16 (bf16) or float.
// 128x128 block tile, 4 waves 2x2 (64x64 each), BK=32, mfma 16x16x32 bf16.
template <int GELU, int RES, typename OUTT>
__global__ __launch_bounds__(256)
void gemm_kernel(const u16* __restrict__ A, const u16* __restrict__ BT,
                 const float* __restrict__ bias, const u16* __restrict__ res,
                 OUTT* __restrict__ C, int M, int N, int K) {
  __shared__ __align__(16) u16 abuf[128 * 32];
  __shared__ __align__(16) u16 bbuf[128 * 32];
  int tid = threadIdx.x;
  int w = tid >> 6, lane = tid & 63, ln = lane & 15, quad = lane >> 4;
  int bm = blockIdx.x * 128, bn = blockIdx.y * 128;
  int wr = w >> 1, wc = w & 1;
  floatx4 acc[4][4] = {};
  for (int k0 = 0; k0 < K; k0 += 32) {
    __syncthreads();
    for (int rd = 0; rd < 2; rd++) {
      int c = tid + rd * 256;           // chunk of 8 bf16
      int row = c >> 2, col = (c & 3) * 8;
      *(uint4*)(abuf + c * 8) = *(const uint4*)(A + (size_t)(bm + row) * K + k0 + col);
      *(uint4*)(bbuf + c * 8) = *(const uint4*)(BT + (size_t)(bn + row) * K + k0 + col);
    }
    __syncthreads();
    short8 af[4], bf[4];
    for (int i = 0; i < 4; i++)
      af[i] = *(const short8*)(abuf + (wr * 64 + i * 16 + ln) * 32 + quad * 8);
    for (int j = 0; j < 4; j++)
      bf[j] = *(const short8*)(bbuf + (wc * 64 + j * 16 + ln) * 32 + quad * 8);
    for (int i = 0; i < 4; i++)
      for (int j = 0; j < 4; j++)
        acc[i][j] = MFMA16(af[i], bf[j], acc[i][j]);
  }
  for (int i = 0; i < 4; i++) {
    int row0 = bm + wr * 64 + i * 16 + quad * 4;
    for (int j = 0; j < 4; j++) {
      int col = bn + wc * 64 + j * 16 + ln;
      float bv = bias[col];
      for (int r = 0; r < 4; r++) {
        float v = acc[i][j][r] + bv;
        if (RES) v += b2f(res[(size_t)(row0 + r) * N + col]);
        if (GELU) v = gelu_f(v);
        if constexpr (sizeof(OUTT) == 2)
          C[(size_t)(row0 + r) * N + col] = f2b(v);
        else
          C[(size_t)(row0 + r) * N + col] = v;
      }
    }
  }
}

// ------------- Flash attention, one (b,h,qtile64) per block -----------------------
// qkv layout: [(b*1024+n)*12 + h][384] bf16, q=[0:128) k=[128:256) v=[256:384)
// obuf layout: [(b*1024+n)*12 + h][128] bf16
__global__ __launch_bounds__(256)
void attn_kernel(const u16* __restrict__ qkv, u16* __restrict__ obuf) {
  int blk = blockIdx.x;
  int qt = blk & 15, bh = blk >> 4;
  int b = bh / 12, hh = bh % 12;
  int tid = threadIdx.x, w = tid >> 6, lane = tid & 63, ln = lane & 15, quad = lane >> 4;
  __shared__ __align__(16) u16 kbuf[32 * 128];  // [key][d]
  __shared__ __align__(16) u16 vbuf[128 * 32];  // [d][key] (transposed)
  __shared__ __align__(16) u16 pbuf[4][16 * 32];
  const int rs = 12 * 384;
  size_t base = (((size_t)b * 1024) * 12 + hh) * 384;
  const u16* qp = qkv + base;
  const u16* kp = qkv + base + 128;
  const u16* vp = qkv + base + 256;

  int qrow = qt * 64 + w * 16 + ln;
  short8 qf[4];
  for (int st = 0; st < 4; st++)
    qf[st] = *(const short8*)(qp + (size_t)qrow * rs + st * 32 + quad * 8);

  floatx4 o[8];
  for (int dt = 0; dt < 8; dt++) o[dt] = (floatx4){0.f, 0.f, 0.f, 0.f};
  float m_[4] = {-1e30f, -1e30f, -1e30f, -1e30f};
  float l_[4] = {0.f, 0.f, 0.f, 0.f};
  const float sc = 0.08838834764831845f;  // 1/sqrt(128)

  for (int kt = 0; kt < 32; kt++) {
    __syncthreads();
    for (int rd = 0; rd < 2; rd++) {
      int c = tid + rd * 256;
      int row = c >> 4, d0 = (c & 15) * 8;
      *(uint4*)(kbuf + c * 8) =
          *(const uint4*)(kp + (size_t)(kt * 32 + row) * rs + d0);
      union { uint4 u; u16 s[8]; } uu;
      uu.u = *(const uint4*)(vp + (size_t)(kt * 32 + row) * rs + d0);
      for (int j = 0; j < 8; j++) vbuf[(d0 + j) * 32 + row] = uu.s[j];
    }
    __syncthreads();

    floatx4 s0 = (floatx4){0.f, 0.f, 0.f, 0.f};
    floatx4 s1 = (floatx4){0.f, 0.f, 0.f, 0.f};
    for (int st = 0; st < 4; st++) {
      short8 bk = *(const short8*)(kbuf + ln * 128 + st * 32 + quad * 8);
      s0 = MFMA16(qf[st], bk, s0);
    }
    for (int st = 0; st < 4; st++) {
      short8 bk = *(const short8*)(kbuf + (16 + ln) * 128 + st * 32 + quad * 8);
      s1 = MFMA16(qf[st], bk, s1);
    }
    float al[4];
    for (int r = 0; r < 4; r++) {
      float a0 = s0[r] * sc, a1 = s1[r] * sc;
      float tm = fmaxf(a0, a1);
      tm = fmaxf(tm, __shfl_xor(tm, 1, 64));
      tm = fmaxf(tm, __shfl_xor(tm, 2, 64));
      tm = fmaxf(tm, __shfl_xor(tm, 4, 64));
      tm = fmaxf(tm, __shfl_xor(tm, 8, 64));
      float mn = fmaxf(m_[r], tm);
      al[r] = expf(m_[r] - mn);
      m_[r] = mn;
      float p0 = expf(a0 - mn), p1 = expf(a1 - mn);
      float ts = p0 + p1;
      ts += __shfl_xor(ts, 1, 64);
      ts += __shfl_xor(ts, 2, 64);
      ts += __shfl_xor(ts, 4, 64);
      ts += __shfl_xor(ts, 8, 64);
      l_[r] = l_[r] * al[r] + ts;
      pbuf[w][(quad * 4 + r) * 32 + ln] = f2b(p0);
      pbuf[w][(quad * 4 + r) * 32 + 16 + ln] = f2b(p1);
    }
    for (int dt = 0; dt < 8; dt++)
      for (int r = 0; r < 4; r++) o[dt][r] *= al[r];
    short8 ap = *(const short8*)(&pbuf[w][ln * 32 + quad * 8]);
    for (int dt = 0; dt < 8; dt++) {
      short8 bv = *(const short8*)(vbuf + (dt * 16 + ln) * 32 + quad * 8);
      o[dt] = MFMA16(ap, bv, o[dt]);
    }
  }

  float inv[4];
  for (int r = 0; r < 4; r++) inv[r] = 1.0f / l_[r];
  for (int dt = 0; dt < 8; dt++) {
    for (int r = 0; r < 4; r++) {
      int n = qt * 64 + w * 16 + quad * 4 + r;
      size_t oi = ((((size_t)b * 1024 + n) * 12) + hh) * 128 + dt * 16 + ln;
      obuf[oi] = f2b(o[dt][r] * inv[r]);
    }
  }
}

// ------------- host ---------------------------------------------------------------
extern "C" void kernel_launch(void* const* d_in, const int* in_sizes, int n_in,
                              void* d_out, int out_size, void* d_ws, size_t ws_size,
                              hipStream_t stream) {
  (void)in_sizes; (void)n_in; (void)out_size; (void)ws_size;
  const float* x    = (const float*)d_in[0];
  const float* ln1g = (const float*)d_in[1];
  const float* ln1b = (const float*)d_in[2];
  const float* W1   = (const float*)d_in[3];
  const float* b1   = (const float*)d_in[4];
  const float* W2   = (const float*)d_in[5];
  const float* b2   = (const float*)d_in[6];
  const float* alng = (const float*)d_in[7];
  const float* alnb = (const float*)d_in[8];
  const float* Wqkv = (const float*)d_in[9];
  const float* bqkv = (const float*)d_in[10];
  const float* Wl   = (const float*)d_in[11];
  const float* bl   = (const float*)d_in[12];
  const float* lnog = (const float*)d_in[13];
  const float* lnob = (const float*)d_in[14];
  const float* Wo   = (const float*)d_in[15];
  const float* bo   = (const float*)d_in[16];
  float* out = (float*)d_out;

  char* ws = (char*)d_ws;
  size_t off = 0;
  auto alloc = [&](size_t elems) { u16* p = (u16*)(ws + off); off += elems * sizeof(u16); return p; };
  u16* w1t   = alloc((size_t)1536 * 128);
  u16* w2t   = alloc((size_t)1536 * 1536);
  u16* wqkvt = alloc((size_t)384 * 128);
  u16* wlt   = alloc((size_t)128 * 128);
  u16* wot   = alloc((size_t)128 * 1536);
  u16* lnx   = alloc((size_t)4096 * 128);
  u16* h1    = alloc((size_t)4096 * 1536);   // reused as attention output
  u16* h2    = alloc((size_t)4096 * 1536);
  u16* aln   = alloc((size_t)49152 * 128);   // reused as feats
  u16* qkv   = alloc((size_t)49152 * 384);   // reused as ln(feats)
  u16* obuf = h1;
  u16* feats = aln;
  u16* lnf = qkv;
  // total ws use: ~82 MB (all intermediates bf16)

  dim3 T(256);
  tpose_kernel<<<dim3(1536 / 32, 128 / 32), T, 0, stream>>>(W1, w1t, 128, 1536);
  tpose_kernel<<<dim3(1536 / 32, 1536 / 32), T, 0, stream>>>(W2, w2t, 1536, 1536);
  tpose_kernel<<<dim3(384 / 32, 128 / 32), T, 0, stream>>>(Wqkv, wqkvt, 128, 384);
  tpose_kernel<<<dim3(128 / 32, 128 / 32), T, 0, stream>>>(Wl, wlt, 128, 128);
  tpose_kernel<<<dim3(128 / 32, 1536 / 32), T, 0, stream>>>(Wo, wot, 1536, 128);

  // project
  ln128_f32_kernel<<<dim3(4096 / 4), T, 0, stream>>>(x, ln1g, ln1b, lnx);
  gemm_kernel<1, 0, u16><<<dim3(4096 / 128, 1536 / 128), T, 0, stream>>>(
      lnx, w1t, b1, nullptr, h1, 4096, 1536, 128);
  gemm_kernel<0, 0, u16><<<dim3(4096 / 128, 1536 / 128), T, 0, stream>>>(
      h1, w2t, b2, nullptr, h2, 4096, 1536, 1536);
  // attention (per-head LN + QKV + flash + Wl + residual GELU), (b,n,h,d) order
  ln128_bf16_kernel<<<dim3(49152 / 4), T, 0, stream>>>(h2, alng, alnb, aln);
  gemm_kernel<0, 0, u16><<<dim3(49152 / 128, 384 / 128), T, 0, stream>>>(
      aln, wqkvt, bqkv, nullptr, qkv, 49152, 384, 128);
  attn_kernel<<<dim3(768), T, 0, stream>>>(qkv, obuf);
  gemm_kernel<1, 1, u16><<<dim3(49152 / 128, 1), T, 0, stream>>>(
      obuf, wlt, bl, h2, feats, 49152, 128, 128);
  // out_proj
  ln1536_kernel<<<dim3(4096), T, 0, stream>>>(feats, lnog, lnob, lnf);
  gemm_kernel<1, 0, float><<<dim3(4096 / 128, 1), T, 0, stream>>>(
      lnf, wot, bo, nullptr, out, 4096, 128, 1536);
}

// Round 3
// 406.959 us; speedup vs baseline: 1.3092x; 1.3092x over previous
//
#include <hip/hip_runtime.h>
#include <stdint.h>

typedef unsigned short u16;
typedef __attribute__((ext_vector_type(8))) short short8;   // 8 bf16 (MFMA A/B frag)
typedef __attribute__((ext_vector_type(4))) float floatx4;  // MFMA C/D frag

__device__ inline float b2f(u16 u) {
  union { uint32_t i; float f; } x; x.i = ((uint32_t)u) << 16; return x.f;
}
__device__ inline u16 f2b(float f) {
  union { float f; uint32_t i; } x; x.f = f;
  uint32_t r = (x.i + 0x7FFFu + ((x.i >> 16) & 1u)) >> 16;
  return (u16)r;
}
__device__ inline float gelu_f(float v) {
  return 0.5f * v * (1.0f + erff(v * 0.70710678118654752440f));
}

#define MFMA16(a, b, c) __builtin_amdgcn_mfma_f32_16x16x32_bf16((a), (b), (c), 0, 0, 0)

// async global->LDS, 16B per lane; LDS dest must be wave-uniform base + lane*16
__device__ __forceinline__ void gl2lds16(const u16* g, u16* l) {
  __builtin_amdgcn_global_load_lds(
      (const __attribute__((address_space(1))) uint32_t*)(uintptr_t)g,
      (__attribute__((address_space(3))) uint32_t*)(uint32_t)(uintptr_t)l,
      16, 0, 0);
}

// ------------- transpose+convert: dst[C][R] = bf16(src[R][C]) (src fp32) ----------
__global__ __launch_bounds__(256)
void tpose_kernel(const float* __restrict__ src, u16* __restrict__ dst, int R, int C) {
  __shared__ u16 t[32][33];
  int bx = blockIdx.x * 32, by = blockIdx.y * 32;
  int tx = threadIdx.x & 31, ty = threadIdx.x >> 5;
  for (int i = 0; i < 32; i += 8)
    t[ty + i][tx] = f2b(src[(size_t)(by + ty + i) * C + bx + tx]);
  __syncthreads();
  for (int i = 0; i < 32; i += 8)
    dst[(size_t)(bx + ty + i) * R + by + tx] = t[tx][ty + i];
}

// ------------- V transpose (bf16): per head, vT[d][n] = qkv_v[n][d] ----------------
__global__ __launch_bounds__(256)
void vtrans_kernel(const u16* __restrict__ qkv, u16* __restrict__ vT) {
  int bh = blockIdx.z;                  // b*12+h
  int n0 = blockIdx.x * 32, d0 = blockIdx.y * 32;
  int b = bh / 12, h = bh % 12;
  const int rs = 12 * 384;
  const u16* vp = qkv + (((size_t)b * 1024) * 12 + h) * 384 + 256;
  __shared__ u16 t[32][33];
  int tx = threadIdx.x & 31, ty = threadIdx.x >> 5;
  for (int i = 0; i < 32; i += 8)
    t[ty + i][tx] = vp[(size_t)(n0 + ty + i) * rs + d0 + tx];
  __syncthreads();
  u16* dp = vT + ((size_t)bh * 128 + d0) * 1024 + n0;
  for (int i = 0; i < 32; i += 8)
    dp[(size_t)(ty + i) * 1024 + tx] = t[tx][ty + i];
}

// ------------- LayerNorm D=128, fp32 source -> bf16 out; one wave per row ---------
__global__ __launch_bounds__(256)
void ln128_f32_kernel(const float* __restrict__ X, const float* __restrict__ g,
                      const float* __restrict__ bb, u16* __restrict__ Y) {
  int tid = threadIdx.x, w = tid >> 6, lane = tid & 63;
  int row = blockIdx.x * 4 + w;
  const float* xr = X + (size_t)row * 128;
  float2 xv = *(const float2*)(xr + lane * 2);
  float x0 = xv.x, x1 = xv.y;
  float s = x0 + x1, s2 = x0 * x0 + x1 * x1;
  for (int m = 1; m < 64; m <<= 1) { s += __shfl_xor(s, m, 64); s2 += __shfl_xor(s2, m, 64); }
  float mean = s * (1.0f / 128.0f);
  float var = s2 * (1.0f / 128.0f) - mean * mean;
  float rstd = 1.0f / sqrtf(var + 1e-5f);
  float2 gv = *(const float2*)(g + lane * 2);
  float2 bv = *(const float2*)(bb + lane * 2);
  float y0 = (x0 - mean) * rstd * gv.x + bv.x;
  float y1 = (x1 - mean) * rstd * gv.y + bv.y;
  *(uint32_t*)(Y + (size_t)row * 128 + lane * 2) =
      (uint32_t)f2b(y0) | ((uint32_t)f2b(y1) << 16);
}

// ------------- LayerNorm D=128, bf16 source -> bf16 out; one wave per row ---------
__global__ __launch_bounds__(256)
void ln128_bf16_kernel(const u16* __restrict__ X, const float* __restrict__ g,
                       const float* __restrict__ bb, u16* __restrict__ Y) {
  int tid = threadIdx.x, w = tid >> 6, lane = tid & 63;
  int row = blockIdx.x * 4 + w;
  const u16* xr = X + (size_t)row * 128;
  uint32_t u = *(const uint32_t*)(xr + lane * 2);
  float x0 = b2f(u & 0xffff), x1 = b2f(u >> 16);
  float s = x0 + x1, s2 = x0 * x0 + x1 * x1;
  for (int m = 1; m < 64; m <<= 1) { s += __shfl_xor(s, m, 64); s2 += __shfl_xor(s2, m, 64); }
  float mean = s * (1.0f / 128.0f);
  float var = s2 * (1.0f / 128.0f) - mean * mean;
  float rstd = 1.0f / sqrtf(var + 1e-5f);
  float2 gv = *(const float2*)(g + lane * 2);
  float2 bv = *(const float2*)(bb + lane * 2);
  float y0 = (x0 - mean) * rstd * gv.x + bv.x;
  float y1 = (x1 - mean) * rstd * gv.y + bv.y;
  *(uint32_t*)(Y + (size_t)row * 128 + lane * 2) =
      (uint32_t)f2b(y0) | ((uint32_t)f2b(y1) << 16);
}

// ------------- LayerNorm D=1536, bf16 source -> bf16 out; one block per row -------
__global__ __launch_bounds__(256)
void ln1536_kernel(const u16* __restrict__ X, const float* __restrict__ g,
                   const float* __restrict__ bb, u16* __restrict__ Y) {
  int row = blockIdx.x, tid = threadIdx.x;
  const u16* xr = X + (size_t)row * 1536;
  uint32_t u0 = *(const uint32_t*)(xr + tid * 6);
  uint32_t u1 = *(const uint32_t*)(xr + tid * 6 + 2);
  uint32_t u2 = *(const uint32_t*)(xr + tid * 6 + 4);
  float v[6] = { b2f(u0 & 0xffff), b2f(u0 >> 16), b2f(u1 & 0xffff),
                 b2f(u1 >> 16),    b2f(u2 & 0xffff), b2f(u2 >> 16) };
  float s = 0.f, s2 = 0.f;
  for (int j = 0; j < 6; j++) { s += v[j]; s2 += v[j] * v[j]; }
  for (int m = 1; m < 64; m <<= 1) { s += __shfl_xor(s, m, 64); s2 += __shfl_xor(s2, m, 64); }
  __shared__ float red[8];
  int w = tid >> 6, lane = tid & 63;
  if (lane == 0) { red[w] = s; red[4 + w] = s2; }
  __syncthreads();
  s = red[0] + red[1] + red[2] + red[3];
  s2 = red[4] + red[5] + red[6] + red[7];
  float mean = s * (1.0f / 1536.0f);
  float var = s2 * (1.0f / 1536.0f) - mean * mean;
  float rstd = 1.0f / sqrtf(var + 1e-5f);
  uint32_t o[3];
  for (int p = 0; p < 3; p++) {
    int c = tid * 6 + p * 2;
    float y0 = (v[p * 2] - mean) * rstd * g[c] + bb[c];
    float y1 = (v[p * 2 + 1] - mean) * rstd * g[c + 1] + bb[c + 1];
    o[p] = (uint32_t)f2b(y0) | ((uint32_t)f2b(y1) << 16);
  }
  u16* yr = Y + (size_t)row * 1536 + tid * 6;
  *(uint32_t*)(yr) = o[0];
  *(uint32_t*)(yr + 2) = o[1];
  *(uint32_t*)(yr + 4) = o[2];
}

// ------------- GEMM: C[M,N] = act(A[M,K] @ BT[N,K]^T + bias (+res)) ---------------
// 128x128 tile, 4 waves 2x2, BK=32, global_load_lds staging (m97 structure).
template <int GELU, int RES, typename OUTT>
__global__ __launch_bounds__(256)
void gemm_kernel(const u16* __restrict__ A, const u16* __restrict__ BT,
                 const float* __restrict__ bias, const u16* __restrict__ res,
                 OUTT* __restrict__ C, int M, int N, int K) {
  __shared__ __align__(16) u16 abuf[128 * 32];
  __shared__ __align__(16) u16 bbuf[128 * 32];
  int tid = threadIdx.x;
  int w = tid >> 6, lane = tid & 63, ln = lane & 15, quad = lane >> 4;
  int bm = blockIdx.x * 128, bn = blockIdx.y * 128;
  int wr = w >> 1, wc = w & 1;
  floatx4 acc[4][4] = {};
  for (int k0 = 0; k0 < K; k0 += 32) {
    __syncthreads();
    for (int rd = 0; rd < 2; rd++) {
      int c = tid + rd * 256;           // 16B chunk id; LDS addr = c*16 (lane-contig)
      int row = c >> 2, col = (c & 3) * 8;
      gl2lds16(A + (size_t)(bm + row) * K + k0 + col, abuf + c * 8);
      gl2lds16(BT + (size_t)(bn + row) * K + k0 + col, bbuf + c * 8);
    }
    __syncthreads();
    short8 af[4], bf[4];
    for (int i = 0; i < 4; i++)
      af[i] = *(const short8*)(abuf + (wr * 64 + i * 16 + ln) * 32 + quad * 8);
    for (int j = 0; j < 4; j++)
      bf[j] = *(const short8*)(bbuf + (wc * 64 + j * 16 + ln) * 32 + quad * 8);
    for (int i = 0; i < 4; i++)
      for (int j = 0; j < 4; j++)
        acc[i][j] = MFMA16(af[i], bf[j], acc[i][j]);
  }
  for (int i = 0; i < 4; i++) {
    int row0 = bm + wr * 64 + i * 16 + quad * 4;
    for (int j = 0; j < 4; j++) {
      int col = bn + wc * 64 + j * 16 + ln;
      float bv = bias[col];
      for (int r = 0; r < 4; r++) {
        float v = acc[i][j][r] + bv;
        if (RES) v += b2f(res[(size_t)(row0 + r) * N + col]);
        if (GELU) v = gelu_f(v);
        if constexpr (sizeof(OUTT) == 2)
          C[(size_t)(row0 + r) * N + col] = f2b(v);
        else
          C[(size_t)(row0 + r) * N + col] = v;
      }
    }
  }
}

// ------------- Flash attention, 64-key tiles, conflict-free LDS -------------------
// qkv: [(b*1024+n)*12+h][384] bf16 (q 0:128, k 128:256)
// vT:  [bh][128 d][1024 n] bf16
// obuf: [(b*1024+n)*12+h][128] bf16
__global__ __launch_bounds__(256)
void attn_kernel(const u16* __restrict__ qkv, const u16* __restrict__ vT,
                 u16* __restrict__ obuf) {
  int blk = blockIdx.x;
  int qt = blk & 15, bh = blk >> 4;
  int b = bh / 12, hh = bh % 12;
  int tid = threadIdx.x, w = tid >> 6, lane = tid & 63, ln = lane & 15, quad = lane >> 4;
  // K tile: kbuf[st][key 64][32]  (st = d-chunk of 32)
  __shared__ __align__(16) u16 kbuf[4 * 64 * 32];
  // V^T tile: vbuf[kf][d 128][32] (kf = key-chunk of 32)
  __shared__ __align__(16) u16 vbuf[2 * 128 * 32];
  __shared__ __align__(16) u16 pbuf[4][16 * 72];  // per-wave P, padded stride 72
  const int rs = 12 * 384;
  size_t base = (((size_t)b * 1024) * 12 + hh) * 384;
  const u16* qp = qkv + base;
  const u16* kp = qkv + base + 128;
  const u16* vp = vT + (size_t)bh * 128 * 1024;

  int qrow = qt * 64 + w * 16 + ln;
  short8 qf[4];
  for (int st = 0; st < 4; st++)
    qf[st] = *(const short8*)(qp + (size_t)qrow * rs + st * 32 + quad * 8);

  floatx4 o[8] = {};
  float m_[4] = {-1e30f, -1e30f, -1e30f, -1e30f};
  float l_[4] = {0.f, 0.f, 0.f, 0.f};
  const float sc = 0.08838834764831845f;  // 1/sqrt(128)

  for (int kt = 0; kt < 16; kt++) {
    __syncthreads();
    for (int it = 0; it < 4; it++) {
      int c = it * 256 + tid;  // c = [st:2][key:6][cc:2] for K; [kf:1][d:7][cc:2] for V
      int st = c >> 8, key = (c >> 2) & 63, cc = c & 3;
      gl2lds16(kp + (size_t)(kt * 64 + key) * rs + st * 32 + cc * 8, kbuf + c * 8);
      int kf = c >> 9, d = (c >> 2) & 127;
      gl2lds16(vp + (size_t)d * 1024 + kt * 64 + kf * 32 + cc * 8, vbuf + c * 8);
    }
    __syncthreads();

    floatx4 s[4] = {};
    for (int t = 0; t < 4; t++)
      for (int st = 0; st < 4; st++) {
        short8 bk = *(const short8*)(kbuf + st * 2048 + (t * 16 + ln) * 32 + quad * 8);
        s[t] = MFMA16(qf[st], bk, s[t]);
      }
    float al[4];
    for (int r = 0; r < 4; r++) {
      float a0 = s[0][r] * sc, a1 = s[1][r] * sc, a2 = s[2][r] * sc, a3 = s[3][r] * sc;
      float tm = fmaxf(fmaxf(a0, a1), fmaxf(a2, a3));
      tm = fmaxf(tm, __shfl_xor(tm, 1, 64));
      tm = fmaxf(tm, __shfl_xor(tm, 2, 64));
      tm = fmaxf(tm, __shfl_xor(tm, 4, 64));
      tm = fmaxf(tm, __shfl_xor(tm, 8, 64));
      float mn = fmaxf(m_[r], tm);
      al[r] = __expf(m_[r] - mn);
      m_[r] = mn;
      float p0 = __expf(a0 - mn), p1 = __expf(a1 - mn);
      float p2 = __expf(a2 - mn), p3 = __expf(a3 - mn);
      float ts = (p0 + p1) + (p2 + p3);
      ts += __shfl_xor(ts, 1, 64);
      ts += __shfl_xor(ts, 2, 64);
      ts += __shfl_xor(ts, 4, 64);
      ts += __shfl_xor(ts, 8, 64);
      l_[r] = l_[r] * al[r] + ts;
      int prow = (quad * 4 + r) * 72;
      pbuf[w][prow + ln] = f2b(p0);
      pbuf[w][prow + 16 + ln] = f2b(p1);
      pbuf[w][prow + 32 + ln] = f2b(p2);
      pbuf[w][prow + 48 + ln] = f2b(p3);
    }
    for (int dt = 0; dt < 8; dt++)
      for (int r = 0; r < 4; r++) o[dt][r] *= al[r];
    for (int kf = 0; kf < 2; kf++) {
      short8 ap = *(const short8*)(&pbuf[w][ln * 72 + kf * 32 + quad * 8]);
      for (int dt = 0; dt < 8; dt++) {
        short8 bv = *(const short8*)(vbuf + kf * 4096 + (dt * 16 + ln) * 32 + quad * 8);
        o[dt] = MFMA16(ap, bv, o[dt]);
      }
    }
  }

  float inv[4];
  for (int r = 0; r < 4; r++) inv[r] = 1.0f / l_[r];
  for (int dt = 0; dt < 8; dt++) {
    for (int r = 0; r < 4; r++) {
      int n = qt * 64 + w * 16 + quad * 4 + r;
      size_t oi = ((((size_t)b * 1024 + n) * 12) + hh) * 128 + dt * 16 + ln;
      obuf[oi] = f2b(o[dt][r] * inv[r]);
    }
  }
}

// ------------- host ---------------------------------------------------------------
extern "C" void kernel_launch(void* const* d_in, const int* in_sizes, int n_in,
                              void* d_out, int out_size, void* d_ws, size_t ws_size,
                              hipStream_t stream) {
  (void)in_sizes; (void)n_in; (void)out_size; (void)ws_size;
  const float* x    = (const float*)d_in[0];
  const float* ln1g = (const float*)d_in[1];
  const float* ln1b = (const float*)d_in[2];
  const float* W1   = (const float*)d_in[3];
  const float* b1   = (const float*)d_in[4];
  const float* W2   = (const float*)d_in[5];
  const float* b2   = (const float*)d_in[6];
  const float* alng = (const float*)d_in[7];
  const float* alnb = (const float*)d_in[8];
  const float* Wqkv = (const float*)d_in[9];
  const float* bqkv = (const float*)d_in[10];
  const float* Wl   = (const float*)d_in[11];
  const float* bl   = (const float*)d_in[12];
  const float* lnog = (const float*)d_in[13];
  const float* lnob = (const float*)d_in[14];
  const float* Wo   = (const float*)d_in[15];
  const float* bo   = (const float*)d_in[16];
  float* out = (float*)d_out;

  char* ws = (char*)d_ws;
  size_t off = 0;
  auto alloc = [&](size_t elems) { u16* p = (u16*)(ws + off); off += elems * sizeof(u16); return p; };
  u16* w1t   = alloc((size_t)1536 * 128);
  u16* w2t   = alloc((size_t)1536 * 1536);
  u16* wqkvt = alloc((size_t)384 * 128);
  u16* wlt   = alloc((size_t)128 * 128);
  u16* wot   = alloc((size_t)128 * 1536);
  u16* lnx   = alloc((size_t)4096 * 128);
  u16* h1    = alloc((size_t)4096 * 1536);   // reused as attention output
  u16* h2    = alloc((size_t)4096 * 1536);
  u16* aln   = alloc((size_t)49152 * 128);   // reused as vT, then feats
  u16* qkv   = alloc((size_t)49152 * 384);   // reused as ln(feats)
  u16* obuf = h1;
  u16* vT = aln;     // 48*128*1024 == 49152*128 — exact fit; aln dead after QKV GEMM
  u16* feats = aln;  // vT dead after attn
  u16* lnf = qkv;    // qkv dead after attn

  dim3 T(256);
  tpose_kernel<<<dim3(1536 / 32, 128 / 32), T, 0, stream>>>(W1, w1t, 128, 1536);
  tpose_kernel<<<dim3(1536 / 32, 1536 / 32), T, 0, stream>>>(W2, w2t, 1536, 1536);
  tpose_kernel<<<dim3(384 / 32, 128 / 32), T, 0, stream>>>(Wqkv, wqkvt, 128, 384);
  tpose_kernel<<<dim3(128 / 32, 128 / 32), T, 0, stream>>>(Wl, wlt, 128, 128);
  tpose_kernel<<<dim3(128 / 32, 1536 / 32), T, 0, stream>>>(Wo, wot, 1536, 128);

  // project
  ln128_f32_kernel<<<dim3(4096 / 4), T, 0, stream>>>(x, ln1g, ln1b, lnx);
  gemm_kernel<1, 0, u16><<<dim3(4096 / 128, 1536 / 128), T, 0, stream>>>(
      lnx, w1t, b1, nullptr, h1, 4096, 1536, 128);
  gemm_kernel<0, 0, u16><<<dim3(4096 / 128, 1536 / 128), T, 0, stream>>>(
      h1, w2t, b2, nullptr, h2, 4096, 1536, 1536);
  // attention
  ln128_bf16_kernel<<<dim3(49152 / 4), T, 0, stream>>>(h2, alng, alnb, aln);
  gemm_kernel<0, 0, u16><<<dim3(49152 / 128, 384 / 128), T, 0, stream>>>(
      aln, wqkvt, bqkv, nullptr, qkv, 49152, 384, 128);
  vtrans_kernel<<<dim3(1024 / 32, 128 / 32, 48), T, 0, stream>>>(qkv, vT);
  attn_kernel<<<dim3(768), T, 0, stream>>>(qkv, vT, obuf);
  gemm_kernel<1, 1, u16><<<dim3(49152 / 128, 1), T, 0, stream>>>(
      obuf, wlt, bl, h2, feats, 49152, 128, 128);
  // out_proj
  ln1536_kernel<<<dim3(4096), T, 0, stream>>>(feats, lnog, lnob, lnf);
  gemm_kernel<1, 0, float><<<dim3(4096 / 128, 1), T, 0, stream>>>(
      lnf, wot, bo, nullptr, out, 4096, 128, 1536);
}